// Round 4
// baseline (11.685 us; speedup 1.0000x reference)
//
#include <hip/hip_runtime.h>

#define NB 8
#define SS 43
#define NQ 13
#define DD 608
#define KK 4
#define NF4 (DD / 4)   // 152 float4 per x-row

// One wave per (b, i, j): speculatively compute the pair-features dot for
// every candidate j; a single ballot decides whether j is in the top-4.
// Each wave writes exactly its own output row (b,i,j,0:4) -> disjoint stores.
__global__ __launch_bounds__(64) void imp_enc_kernel(
    const float* __restrict__ x, const float* __restrict__ scores,
    const float* __restrict__ Wff, const float* __restrict__ bff,
    float* __restrict__ out)
{
    const int blk  = blockIdx.x;          // 0 .. B*NQ*NQ-1
    const int bi   = blk / NQ;            // (b,i) group
    const int j    = blk % NQ;            // candidate row this wave owns
    const int b    = bi / NQ;
    const int i    = bi % NQ;
    const int lane = threadIdx.x;

    const float4* W4  = (const float4*)Wff;   // row e: W_top = W4[e], W_bot = W4[DD+e]
    const float4* xs4 = (const float4*)(x + ((size_t)b * SS + i) * DD);
    const float4* xj4 = (const float4*)(x + ((size_t)b * SS + j) * DD);

    // all loads issue immediately; nothing depends on the top-k
    float4 bias = *(const float4*)bff;
    const float* srow = scores + ((size_t)b * SS + i) * SS;
    float myv = (lane < NQ) ? srow[lane] : -INFINITY;   // lane m holds score[m]

    float accS[4] = {0.f, 0.f, 0.f, 0.f};
    float accG[4] = {0.f, 0.f, 0.f, 0.f};
    #pragma unroll
    for (int it = 0; it < 3; ++it) {
        const int f = lane + it * 64;
        if (f < NF4) {
            float4 xv = xs4[f];
            float4 gv = xj4[f];
            const float xe[4] = {xv.x, xv.y, xv.z, xv.w};
            const float ge[4] = {gv.x, gv.y, gv.z, gv.w};
            #pragma unroll
            for (int u = 0; u < 4; ++u) {
                float4 wt = W4[f * 4 + u];
                float4 wb = W4[DD + f * 4 + u];
                accS[0] += xe[u] * wt.x;  accG[0] += ge[u] * wb.x;
                accS[1] += xe[u] * wt.y;  accG[1] += ge[u] * wb.y;
                accS[2] += xe[u] * wt.z;  accG[2] += ge[u] * wb.z;
                accS[3] += xe[u] * wt.w;  accG[3] += ge[u] * wb.w;
            }
        }
    }

    // ---- is j in the top-4?  rank(j) = #{m : v_m > v_j or (v_m == v_j and m < j)} ----
    const float vj = __shfl(myv, j, 64);
    const unsigned long long better =
        __ballot(lane < NQ && (myv > vj || (myv == vj && lane < j)));
    const bool selected = __popcll(better) < KK;   // wave-uniform

    // ---- butterfly reduce 8 values across the wave ----
    #pragma unroll
    for (int off = 32; off > 0; off >>= 1) {
        #pragma unroll
        for (int c = 0; c < 4; ++c) {
            accS[c] += __shfl_xor(accS[c], off, 64);
            accG[c] += __shfl_xor(accG[c], off, 64);
        }
    }

    // ---- lanes 0..3 write this wave's 4 outputs ----
    if (lane < 4) {
        const int c = lane;
        const float vS = (c & 2) ? ((c & 1) ? accS[3] : accS[2])
                                 : ((c & 1) ? accS[1] : accS[0]);
        const float vG = (c & 2) ? ((c & 1) ? accG[3] : accG[2])
                                 : ((c & 1) ? accG[1] : accG[0]);
        const float bc = (c & 2) ? ((c & 1) ? bias.w : bias.z)
                                 : ((c & 1) ? bias.y : bias.x);
        const float val = selected ? (vS + vG + bc) : ((c == 0) ? 1.0f : 0.0f);
        out[(size_t)blk * 4 + c] = val;
    }
}

extern "C" void kernel_launch(void* const* d_in, const int* in_sizes, int n_in,
                              void* d_out, int out_size, void* d_ws, size_t ws_size,
                              hipStream_t stream) {
    const float* x      = (const float*)d_in[0];
    const float* scores = (const float*)d_in[1];
    const float* Wff    = (const float*)d_in[2];
    const float* bff    = (const float*)d_in[3];
    float* out = (float*)d_out;

    imp_enc_kernel<<<NB * NQ * NQ, 64, 0, stream>>>(x, scores, Wff, bff, out);
}

// Round 5
// 11.435 us; speedup vs baseline: 1.0218x; 1.0218x over previous
//
#include <hip/hip_runtime.h>

#define NB 8
#define SS 43
#define NQ 13
#define DD 608
#define KK 4
#define NF4 (DD / 4)   // 152 float4 per x-row

__global__ __launch_bounds__(256) void imp_enc_kernel(
    const float* __restrict__ x, const float* __restrict__ scores,
    const float* __restrict__ Wff, const float* __restrict__ bff,
    float* __restrict__ out)
{
    const int bi   = blockIdx.x;            // 0 .. B*NQ-1
    const int b    = bi / NQ;
    const int i    = bi % NQ;
    const int k    = threadIdx.x >> 6;      // wave id 0..3 = which gather this wave owns
    const int lane = threadIdx.x & 63;

    const float4* W4  = (const float4*)Wff;   // row e: W_top = W4[e], W_bot = W4[DD+e]
    const float4* xs4 = (const float4*)(x + ((size_t)b * SS + i) * DD);

    // ---- scores: uniform (scalar) loads + one coalesced lane load, both issue first ----
    const float* srow = scores + ((size_t)b * SS + i) * SS;
    float sv[NQ];
    #pragma unroll
    for (int m = 0; m < NQ; ++m) sv[m] = srow[m];       // block-uniform -> s_load
    float myv = (lane < NQ) ? srow[lane] : -INFINITY;   // lane j holds score[j]
    float4 bias = *(const float4*)bff;

    // ---- rank of this lane's candidate: 13 VGPR-vs-SGPR compares, no shuffles ----
    // rank_j = #{m : v_m > v_j || (v_m == v_j && m < j)}  (matches lax.top_k ties)
    int rank = 0;
    #pragma unroll
    for (int m = 0; m < NQ; ++m)
        rank += (sv[m] > myv || (sv[m] == myv && m < lane)) ? 1 : 0;

    int idx[KK];
    #pragma unroll
    for (int kk = 0; kk < KK; ++kk) {
        unsigned long long msk = __ballot(lane < NQ && rank == kk);
        idx[kk] = (int)__ffsll(msk) - 1;   // wave-uniform
    }

    // ---- issue this wave's gather loads IMMEDIATELY after top-k resolves ----
    const float4* xg4 = (const float4*)(x + ((size_t)b * SS + idx[k]) * DD);
    float4 gv0, gv1, gv2;
    {
        const int f0 = lane, f1 = lane + 64, f2 = lane + 128;
        gv0 = xg4[f0];
        gv1 = xg4[f1];
        gv2 = (f2 < NF4) ? xg4[f2] : make_float4(0.f, 0.f, 0.f, 0.f);
    }

    // ---- self-row dot W_top: FMA work here hides the gather-load latency ----
    float acc[4] = {0.f, 0.f, 0.f, 0.f};
    #pragma unroll
    for (int it = 0; it < 3; ++it) {
        const int f = lane + it * 64;
        if (f < NF4) {
            float4 xv = xs4[f];
            const float xe[4] = {xv.x, xv.y, xv.z, xv.w};
            #pragma unroll
            for (int u = 0; u < 4; ++u) {
                float4 wt = W4[f * 4 + u];
                acc[0] += xe[u] * wt.x;
                acc[1] += xe[u] * wt.y;
                acc[2] += xe[u] * wt.z;
                acc[3] += xe[u] * wt.w;
            }
        }
    }

    // ---- gather-row dot W_bot, accumulated into the same acc (sum before reduce) ----
    #pragma unroll
    for (int it = 0; it < 3; ++it) {
        const int f = lane + it * 64;
        if (f < NF4) {
            float4 gvv = (it == 0) ? gv0 : (it == 1) ? gv1 : gv2;
            const float ge[4] = {gvv.x, gvv.y, gvv.z, gvv.w};
            #pragma unroll
            for (int u = 0; u < 4; ++u) {
                float4 wb = W4[DD + f * 4 + u];
                acc[0] += ge[u] * wb.x;
                acc[1] += ge[u] * wb.y;
                acc[2] += ge[u] * wb.z;
                acc[3] += ge[u] * wb.w;
            }
        }
    }

    // ---- butterfly reduce 4 values across the wave ----
    #pragma unroll
    for (int off = 32; off > 0; off >>= 1) {
        #pragma unroll
        for (int c = 0; c < 4; ++c) acc[c] += __shfl_xor(acc[c], off, 64);
    }

    // ---- write: wave k owns row j=idx[k]; wave 0 also writes the base rows ----
    if (lane < NQ * 4) {
        const int j = lane >> 2;
        const int c = lane & 3;
        const float vA = (c & 2) ? ((c & 1) ? acc[3] : acc[2])
                                 : ((c & 1) ? acc[1] : acc[0]);
        const float bc = (c & 2) ? ((c & 1) ? bias.w : bias.z)
                                 : ((c & 1) ? bias.y : bias.x);
        const bool sel = (j == idx[0]) | (j == idx[1]) | (j == idx[2]) | (j == idx[3]);
        float* orow = out + (size_t)bi * (NQ * 4);
        if (j == idx[k]) {
            orow[lane] = vA + bc;                   // selected row (self + gather + bias)
        } else if (k == 0 && !sel) {
            orow[lane] = (c == 0) ? 1.0f : 0.0f;    // base rows, disjoint addresses
        }
    }
}

extern "C" void kernel_launch(void* const* d_in, const int* in_sizes, int n_in,
                              void* d_out, int out_size, void* d_ws, size_t ws_size,
                              hipStream_t stream) {
    const float* x      = (const float*)d_in[0];
    const float* scores = (const float*)d_in[1];
    const float* Wff    = (const float*)d_in[2];
    const float* bff    = (const float*)d_in[3];
    float* out = (float*)d_out;

    imp_enc_kernel<<<NB * NQ, 256, 0, stream>>>(x, scores, Wff, bff, out);
}

// Round 6
// 9.932 us; speedup vs baseline: 1.1764x; 1.1513x over previous
//
#include <hip/hip_runtime.h>

#define NB 8
#define SS 43
#define NQ 13
#define DD 608
#define KK 4
#define NF4 (DD / 4)          // 152 float4 per x-row
#define PF4 (NQ * NF4)        // 1976 float4 covering x[b, 0:13, :] (contiguous)

__global__ __launch_bounds__(256) void imp_enc_kernel(
    const float* __restrict__ x, const float* __restrict__ scores,
    const float* __restrict__ Wff, const float* __restrict__ bff,
    float* __restrict__ out)
{
    const int bi   = blockIdx.x;            // 0 .. B*NQ-1
    const int b    = bi / NQ;
    const int i    = bi % NQ;
    const int tid  = threadIdx.x;
    const int k    = tid >> 6;              // wave id 0..3 = which gather this wave owns
    const int lane = tid & 63;

    const float4* W4  = (const float4*)Wff;                 // row e: W_top = W4[e], W_bot = W4[DD+e]
    const float4* xb4 = (const float4*)(x + (size_t)b * SS * DD);  // rows 0..12 are contiguous
    const float4* xs4 = xb4 + (size_t)i * NF4;

    // ---- prefetch the whole candidate slab x[b,0:13,:] into L1/L2 ----
    // (the post-top-k gather then hits cache instead of a ~900cy cold HBM miss)
    #pragma unroll
    for (int r = 0; r < 8; ++r) {
        const int q = tid + r * 256;
        if (q < PF4) {
            float4 pf = xb4[q];
            asm volatile("" :: "v"(pf.x), "v"(pf.y), "v"(pf.z), "v"(pf.w));
        }
    }

    // early independent loads
    float4 bias = *(const float4*)bff;
    const float* srow = scores + ((size_t)b * SS + i) * SS;
    float myv = (lane < NQ) ? srow[lane] : -INFINITY;   // coalesced, lane j holds score j

    // ---- self-row dot W_top (independent of top-k; hides score-load latency) ----
    float acc[4] = {0.f, 0.f, 0.f, 0.f};
    #pragma unroll
    for (int it = 0; it < 3; ++it) {
        const int f = lane + it * 64;
        if (f < NF4) {
            float4 xv = xs4[f];
            const float xe[4] = {xv.x, xv.y, xv.z, xv.w};
            #pragma unroll
            for (int u = 0; u < 4; ++u) {
                float4 wt = W4[f * 4 + u];
                acc[0] += xe[u] * wt.x;
                acc[1] += xe[u] * wt.y;
                acc[2] += xe[u] * wt.z;
                acc[3] += xe[u] * wt.w;
            }
        }
    }

    // ---- lane-parallel top-4 (each wave computes it redundantly; no barrier) ----
    // rank = #elements strictly better; ties -> lower index (matches lax.top_k)
    int rank = 0;
    #pragma unroll
    for (int m = 0; m < NQ; ++m) {
        float vm = __shfl(myv, m, 64);
        if (vm > myv || (vm == myv && m < lane)) ++rank;
    }
    int idx[KK];
    #pragma unroll
    for (int kk = 0; kk < KK; ++kk) {
        unsigned long long msk = __ballot(lane < NQ && rank == kk);
        idx[kk] = (int)__ffsll(msk) - 1;   // wave-uniform
    }

    // ---- this wave's gathered row dot W_bot (row is now cache-warm) ----
    const float4* xg4 = xb4 + (size_t)idx[k] * NF4;
    #pragma unroll
    for (int it = 0; it < 3; ++it) {
        const int f = lane + it * 64;
        if (f < NF4) {
            float4 gv = xg4[f];
            const float ge[4] = {gv.x, gv.y, gv.z, gv.w};
            #pragma unroll
            for (int u = 0; u < 4; ++u) {
                float4 wb = W4[DD + f * 4 + u];
                acc[0] += ge[u] * wb.x;
                acc[1] += ge[u] * wb.y;
                acc[2] += ge[u] * wb.z;
                acc[3] += ge[u] * wb.w;
            }
        }
    }

    // ---- butterfly reduce 4 values across the wave (accS+accG pre-merged) ----
    #pragma unroll
    for (int off = 32; off > 0; off >>= 1) {
        #pragma unroll
        for (int c = 0; c < 4; ++c) acc[c] += __shfl_xor(acc[c], off, 64);
    }

    // ---- write: wave k owns row j=idx[k]; wave 0 also writes base rows ----
    if (lane < NQ * 4) {
        const int j = lane >> 2;
        const int c = lane & 3;
        // explicit select chains (no runtime register-array indexing, rule #20)
        const float vA = (c & 2) ? ((c & 1) ? acc[3] : acc[2])
                                 : ((c & 1) ? acc[1] : acc[0]);
        const float bc = (c & 2) ? ((c & 1) ? bias.w : bias.z)
                                 : ((c & 1) ? bias.y : bias.x);
        const bool sel = (j == idx[0]) | (j == idx[1]) | (j == idx[2]) | (j == idx[3]);
        float* orow = out + (size_t)bi * (NQ * 4);
        if (j == idx[k]) {
            orow[lane] = vA + bc;                   // this wave's selected row
        } else if (k == 0 && !sel) {
            orow[lane] = (c == 0) ? 1.0f : 0.0f;    // base rows, disjoint addresses
        }
    }
}

extern "C" void kernel_launch(void* const* d_in, const int* in_sizes, int n_in,
                              void* d_out, int out_size, void* d_ws, size_t ws_size,
                              hipStream_t stream) {
    const float* x      = (const float*)d_in[0];
    const float* scores = (const float*)d_in[1];
    const float* Wff    = (const float*)d_in[2];
    const float* bff    = (const float*)d_in[3];
    float* out = (float*)d_out;

    imp_enc_kernel<<<NB * NQ, 256, 0, stream>>>(x, scores, Wff, bff, out);
}